// Round 9
// baseline (3901.856 us; speedup 1.0000x reference)
//
#include <hip/hip_runtime.h>
#include <stdint.h>

// fasterRCNNAttentionMinus — MI355X, round 9 (r8 resubmit; r8 never ran).
// Root cause of the triple-identical absmax 0.4375 (r3/r5/r7): pos = pe@wp
// was computed in bf16 MFMA (~3e-4 ABSOLUTE noise). The reference's
// log(max(relu(z),1e-6)) amplifies absolute noise near z=0 unboundedly:
// in groups where nearly all keys clamp to 1e-6, one key pushed from
// z~-1e-4 to +3e-4 gets ~300x the weight of every other key -> s~0.5 vs
// ref 1/300 -> ~0.44 output error. pos_kernel was byte-identical across
// r3/r5/r7 -> identical failures regardless of attn-core rewrites.
// FIX: split-precision MFMA (pe = hi+mid+lo bf16, wp = hi+lo bf16, 5 MFMAs)
// -> ~1e-7 absolute accuracy, f32-equivalent at the clamp scale. POSW
// storage stays bf16 (relative error harmless; absolute error in z was
// fatal). Attn core stays the dumb f32 kernel; optimize only after a PASS.

#define NROWS 4096
#define NONGT 300
#define GRP   16
#define NM    (NROWS * NONGT)   // 1228800

typedef __bf16 bf16;
typedef __bf16 bf16x8 __attribute__((ext_vector_type(8)));
typedef __bf16 bf16x4 __attribute__((ext_vector_type(4)));
typedef float  f32x4  __attribute__((ext_vector_type(4)));

#define MFMA16(a, b, c) __builtin_amdgcn_mfma_f32_16x16x32_bf16((a), (b), (c), 0, 0, 0)

static __device__ __forceinline__ void gload_lds16(const void* g, void* l) {
  __builtin_amdgcn_global_load_lds(
      (const __attribute__((address_space(1))) unsigned int*)(uintptr_t)g,
      (__attribute__((address_space(3))) unsigned int*)(uintptr_t)l, 16, 0, 0);
}

static __device__ __forceinline__ f32x4 zero4() {
  f32x4 z = {0.f, 0.f, 0.f, 0.f};
  return z;
}

// ---------------------------------------------------------------------------
// cast f32 -> bf16, batched via gridDim.y (dst offset = (b&1)*s1 + (b>>1)*s2)
// ---------------------------------------------------------------------------
__global__ void cast_kernel(const float* __restrict__ src, bf16* __restrict__ dst,
                            int n8, long srcStride, long s1, long s2) {
  int b = blockIdx.y;
  src += (size_t)b * srcStride;
  dst += (size_t)(b & 1) * s1 + (size_t)(b >> 1) * s2;
  int u = blockIdx.x * 256 + threadIdx.x;
  if (u < n8) {
    f32x4 a = *(const f32x4*)(src + (size_t)u * 8);
    f32x4 c = *(const f32x4*)(src + (size_t)u * 8 + 4);
    bf16x8 o;
    o[0] = (bf16)a[0]; o[1] = (bf16)a[1]; o[2] = (bf16)a[2]; o[3] = (bf16)a[3];
    o[4] = (bf16)c[0]; o[5] = (bf16)c[1]; o[6] = (bf16)c[2]; o[7] = (bf16)c[3];
    *(bf16x8*)(dst + (size_t)u * 8) = o;
  }
}

// ---------------------------------------------------------------------------
// transpose + cast: src (R,C) f32 row-major -> dst (C,R) bf16 row-major.
// ---------------------------------------------------------------------------
__global__ __launch_bounds__(256) void tcast_kernel(const float* __restrict__ src,
                                                    bf16* __restrict__ dst, int R, int C,
                                                    long srcStride, long s1, long s2) {
  __shared__ alignas(16) float T[64][68];
  int b = blockIdx.y;
  src += (size_t)b * srcStride;
  dst += (size_t)(b & 1) * s1 + (size_t)(b >> 1) * s2;
  int ctiles = C / 64;
  int rt = blockIdx.x / ctiles, ct = blockIdx.x % ctiles;
  int r0 = rt * 64, c0 = ct * 64;
  int tid = threadIdx.x;
#pragma unroll
  for (int rep = 0; rep < 4; ++rep) {
    int u = rep * 256 + tid;
    int r = u >> 4, c4 = u & 15;
    f32x4 v = *(const f32x4*)(src + (size_t)(r0 + r) * C + c0 + c4 * 4);
    *(f32x4*)&T[r][c4 * 4] = v;
  }
  __syncthreads();
#pragma unroll
  for (int rep = 0; rep < 2; ++rep) {
    int u = rep * 256 + tid;
    int cc = u >> 3, r8 = u & 7;
    bf16x8 o;
#pragma unroll
    for (int j = 0; j < 8; ++j) o[j] = (bf16)T[r8 * 8 + j][cc];
    *(bf16x8*)(dst + (size_t)(c0 + cc) * R + r0 + r8 * 8) = o;
  }
}

// ---------------------------------------------------------------------------
// pos kernel, SPLIT-PRECISION: POSW[c][n*300+m] = max(pe@wp + bp, 1e-6)
// computed to ~1e-7 absolute accuracy via pe = hi+mid+lo (bf16) and
// wp = hi+lo (bf16): acc = h*wh + h*wl + m*wh + m*wl + l*wh  (f32 accum).
// Block = 128 pe rows. c covers NC calls x 16 groups; i0 = first call idx.
// ---------------------------------------------------------------------------
template <int NC>
__global__ __launch_bounds__(256) void pos_kernel(const float* __restrict__ pe,
                                                  const float* __restrict__ wp,   // (4,64,16)
                                                  const float* __restrict__ bp,   // (4,16)
                                                  bf16* __restrict__ POSW, int i0) {
  __shared__ alignas(16) bf16 Ah[128][72];
  __shared__ alignas(16) bf16 Am[128][72];
  __shared__ alignas(16) bf16 Al[128][72];
  __shared__ alignas(16) bf16 Bh[NC * 16][72];
  __shared__ alignas(16) bf16 Bl[NC * 16][72];
  __shared__ alignas(16) bf16 Tr[NC * 16][136];
  int tid = threadIdx.x;
  int w = tid >> 6, lane = tid & 63;
  int l15 = lane & 15, lg = lane >> 4;
  size_t nm0 = (size_t)blockIdx.x * 128;

  // wp (call i, d, g) -> Bh/Bl[c=i*16+g][d]  (2-way split)
#pragma unroll
  for (int rep = 0; rep < NC * 4; ++rep) {
    int q = rep * 256 + tid;                 // 0..NC*1024-1
    int i = q >> 10, rem = q & 1023;
    int d = rem >> 4, gg = rem & 15;
    float v = wp[i0 * 1024 + q];
    bf16 h = (bf16)v;
    float r1 = v - (float)h;
    Bh[i * 16 + gg][d] = h;
    Bl[i * 16 + gg][d] = (bf16)r1;
  }
  // pe block (128 x 64) -> Ah/Am/Al (3-way split)
#pragma unroll
  for (int rep = 0; rep < 8; ++rep) {
    int u = rep * 256 + tid;                 // float4 units over 128x64
    int r = u >> 4, c4 = u & 15;
    f32x4 v = *(const f32x4*)(pe + (nm0 + r) * 64 + c4 * 4);
    bf16x4 oh, om, ol;
#pragma unroll
    for (int j = 0; j < 4; ++j) {
      float x = v[j];
      bf16 h = (bf16)x;
      float r1 = x - (float)h;
      bf16 m = (bf16)r1;
      float r2 = r1 - (float)m;
      oh[j] = h; om[j] = m; ol[j] = (bf16)r2;
    }
    *(bf16x4*)&Ah[r][c4 * 4] = oh;
    *(bf16x4*)&Am[r][c4 * 4] = om;
    *(bf16x4*)&Al[r][c4 * 4] = ol;
  }
  __syncthreads();

  bf16x8 bh[NC][2], bl[NC][2];
#pragma unroll
  for (int ctl = 0; ctl < NC; ++ctl)
#pragma unroll
    for (int kc = 0; kc < 2; ++kc) {
      bh[ctl][kc] = *(const bf16x8*)&Bh[ctl * 16 + l15][kc * 32 + lg * 8];
      bl[ctl][kc] = *(const bf16x8*)&Bl[ctl * 16 + l15][kc * 32 + lg * 8];
    }

  f32x4 acc[2][NC];
#pragma unroll
  for (int mt = 0; mt < 2; ++mt)
#pragma unroll
    for (int ctl = 0; ctl < NC; ++ctl) acc[mt][ctl] = zero4();

#pragma unroll
  for (int mt = 0; mt < 2; ++mt) {     // wave w owns rows w*32 + mt*16 + [0,16)
#pragma unroll
    for (int kc = 0; kc < 2; ++kc) {
      bf16x8 ah = *(const bf16x8*)&Ah[w * 32 + mt * 16 + l15][kc * 32 + lg * 8];
      bf16x8 am = *(const bf16x8*)&Am[w * 32 + mt * 16 + l15][kc * 32 + lg * 8];
      bf16x8 al = *(const bf16x8*)&Al[w * 32 + mt * 16 + l15][kc * 32 + lg * 8];
#pragma unroll
      for (int ctl = 0; ctl < NC; ++ctl) {
        acc[mt][ctl] = MFMA16(ah, bh[ctl][kc], acc[mt][ctl]);
        acc[mt][ctl] = MFMA16(ah, bl[ctl][kc], acc[mt][ctl]);
        acc[mt][ctl] = MFMA16(am, bh[ctl][kc], acc[mt][ctl]);
        acc[mt][ctl] = MFMA16(am, bl[ctl][kc], acc[mt][ctl]);
        acc[mt][ctl] = MFMA16(al, bh[ctl][kc], acc[mt][ctl]);
      }
    }
  }
  // epilogue: +bias (f32), clamp at 1e-6, transpose via LDS, bf16 store
#pragma unroll
  for (int ctl = 0; ctl < NC; ++ctl) {
    int c = ctl * 16 + l15;
    float bpv = bp[i0 * 16 + c];
#pragma unroll
    for (int mt = 0; mt < 2; ++mt) {
#pragma unroll
      for (int r = 0; r < 4; ++r) {
        int n = w * 32 + mt * 16 + lg * 4 + r;
        float pv = fmaxf(acc[mt][ctl][r] + bpv, 1e-6f);
        Tr[c][n] = (bf16)pv;
      }
    }
  }
  __syncthreads();
#pragma unroll
  for (int rep = 0; rep < NC; ++rep) {
    int u = rep * 256 + tid;                 // NC*256 chunks of 8 over [NC*16][128]
    int c = u >> 4, n8 = u & 15;
    bf16x8 v = *(const bf16x8*)&Tr[c][n8 * 8];
    *(bf16x8*)(POSW + (size_t)c * NM + nm0 + n8 * 8) = v;
  }
}

// ---------------------------------------------------------------------------
// GEMM: C = A(MxK) @ BT(NxK)^T [+ bias]. bf16 in, f32 accum. 64x128 tile,
// BK=32, dbuf LDS via global_load_lds w=16. ROW-MAJOR epilogue only.
// ---------------------------------------------------------------------------
__global__ __launch_bounds__(256) void gemm64_kernel(
    const bf16* __restrict__ A, int lda, const bf16* __restrict__ BT, int ldb,
    const float* __restrict__ bias, int bias_n,
    float* __restrict__ Cf, bf16* __restrict__ Cb, int ldc, int N, int K) {
  __shared__ alignas(16) bf16 As[2][64][32];
  __shared__ alignas(16) bf16 Bs[2][128][32];
  int tid = threadIdx.x;
  int w = tid >> 6, lane = tid & 63;
  int l15 = lane & 15, lg = lane >> 4;
  int nb = N / 128;
  int mb = blockIdx.x / nb, nbk = blockIdx.x % nb;
  int row0 = mb * 64, col0 = nbk * 128;
  int srow = lane >> 2;                 // 0..15
  int scol8 = (lane & 3) * 8;           // element offset (16B)
  int KT = K / 32;

  f32x4 acc[4][2];
#pragma unroll
  for (int i = 0; i < 4; ++i)
#pragma unroll
    for (int j = 0; j < 2; ++j) acc[i][j] = zero4();

  auto stage = [&](int buf, int k0) {
    gload_lds16(A + (size_t)(row0 + w * 16 + srow) * lda + k0 + scol8, &As[buf][w * 16][0]);
#pragma unroll
    for (int j = 0; j < 2; ++j)
      gload_lds16(BT + (size_t)(col0 + w * 32 + j * 16 + srow) * ldb + k0 + scol8,
                  &Bs[buf][w * 32 + j * 16][0]);
  };

  stage(0, 0);
  for (int kt = 0; kt < KT; ++kt) {
    int cur = kt & 1;
    __syncthreads();                       // compiler drains vmcnt before barrier
    if (kt + 1 < KT) stage(cur ^ 1, (kt + 1) * 32);
    bf16x8 af[4], bf_[2];
#pragma unroll
    for (int mt = 0; mt < 4; ++mt)
      af[mt] = *(const bf16x8*)&As[cur][mt * 16 + l15][lg * 8];
#pragma unroll
    for (int nt = 0; nt < 2; ++nt)
      bf_[nt] = *(const bf16x8*)&Bs[cur][w * 32 + nt * 16 + l15][lg * 8];
#pragma unroll
    for (int mt = 0; mt < 4; ++mt)
#pragma unroll
      for (int nt = 0; nt < 2; ++nt) acc[mt][nt] = MFMA16(af[mt], bf_[nt], acc[mt][nt]);
  }

#pragma unroll
  for (int nt = 0; nt < 2; ++nt) {
    int col = col0 + w * 32 + nt * 16 + l15;
    float bv = (bias && col < bias_n) ? bias[col] : 0.0f;
#pragma unroll
    for (int mt = 0; mt < 4; ++mt) {
      int rowb = row0 + mt * 16 + lg * 4;
#pragma unroll
      for (int r = 0; r < 4; ++r) {
        float v = acc[mt][nt][r] + bv;
        size_t idx = (size_t)(rowb + r) * ldc + col;
        if (Cf) Cf[idx] = v;
        if (Cb) Cb[idx] = (bf16)v;
      }
    }
  }
}

// ---------------------------------------------------------------------------
// SIMPLE attention pair core. One block per (n, g). All arithmetic f32;
// Q/K/V/pos read as bf16 and upcast; Pin is f32.
// ---------------------------------------------------------------------------
__global__ __launch_bounds__(256) void attn_simple_kernel(
    const bf16* __restrict__ Q, const bf16* __restrict__ K,
    const bf16* __restrict__ V, const bf16* __restrict__ PosW,
    const float* __restrict__ Pin,
    const float* __restrict__ bc0, const float* __restrict__ bc1,
    float* __restrict__ Of, bf16* __restrict__ Ob) {
  __shared__ float s_q[64];
  __shared__ float s_w[300];
  __shared__ float s_p[4][64];
  __shared__ float s_red;
  int n = blockIdx.x;
  int g = blockIdx.y;
  int tid = threadIdx.x;
  float pacc = 0.f;                       // threads tid<64 own output col o=tid

  for (int ii = 0; ii < 2; ++ii) {
    int base = ii * 1024 + g * 64;
    if (tid < 64) s_q[tid] = (float)Q[(size_t)n * 2048 + base + tid];
    __syncthreads();
    for (int m = tid; m < NONGT; m += 256) {        // strided: 256 threads, 300 keys
      const bf16* krow = K + (size_t)m * 2048 + base;
      float a = 0.f;
      for (int d = 0; d < 64; ++d) a += s_q[d] * (float)krow[d];
      s_w[m] = a * 0.125f;
    }
    __syncthreads();
    if (tid < 64) {
      float mx = -1e30f;
      for (int m = tid; m < NONGT; m += 64) mx = fmaxf(mx, s_w[m]);
      for (int d = 1; d < 64; d <<= 1) mx = fmaxf(mx, __shfl_xor(mx, d, 64));
      if (tid == 0) s_red = mx;
    }
    __syncthreads();
    float mx = s_red;
    __syncthreads();
    for (int m = tid; m < NONGT; m += 256) {        // strided
      float pv = (float)PosW[(size_t)(ii * GRP + g) * NM + (size_t)n * NONGT + m];
      s_w[m] = pv * __expf(s_w[m] - mx);
    }
    __syncthreads();
    if (tid < 64) {
      float sm = 0.f;
      for (int m = tid; m < NONGT; m += 64) sm += s_w[m];
      for (int d = 1; d < 64; d <<= 1) sm += __shfl_xor(sm, d, 64);
      if (tid == 0) s_red = sm;
    }
    __syncthreads();
    float sc = ((ii == 0) ? 1.f : -1.f) / s_red;
    {
      int o = tid & 63, sl = tid >> 6;              // 4 slabs x 75 keys
      float p = 0.f;
      for (int m = sl * 75; m < sl * 75 + 75; ++m)
        p += s_w[m] * (float)V[(size_t)m * 2048 + base + o];
      s_p[sl][o] = p;
    }
    __syncthreads();
    if (tid < 64) pacc += sc * (s_p[0][tid] + s_p[1][tid] + s_p[2][tid] + s_p[3][tid]);
    __syncthreads();   // s_q/s_w/s_p/s_red dead before next ii reuses them
  }
  if (tid < 64) {
    int col = g * 64 + tid;
    size_t idx = (size_t)n * 1024 + col;
    float v = pacc + Pin[idx] + bc0[col] - bc1[col];
    if (Of) Of[idx] = v;
    if (Ob) Ob[idx] = (bf16)v;
  }
}

// ---------------------------------------------------------------------------
extern "C" void kernel_launch(void* const* d_in, const int* in_sizes, int n_in,
                              void* d_out, int out_size, void* d_ws, size_t ws_size,
                              hipStream_t stream) {
  (void)in_sizes; (void)n_in; (void)out_size;
  const float* pooled = (const float*)d_in[0];
  const float* pe     = (const float*)d_in[1];
  const float* fc1w   = (const float*)d_in[2];
  const float* fc1b   = (const float*)d_in[3];
  const float* fc2w   = (const float*)d_in[4];
  const float* fc2b   = (const float*)d_in[5];
  const float* awp    = (const float*)d_in[6];
  const float* abp    = (const float*)d_in[7];
  const float* awq    = (const float*)d_in[8];
  const float* abq    = (const float*)d_in[9];
  const float* awk    = (const float*)d_in[10];
  const float* abk    = (const float*)d_in[11];
  const float* awc    = (const float*)d_in[12];
  const float* abc    = (const float*)d_in[13];
  float* out = (float*)d_out;

  char* basep = (char*)d_ws;
  size_t off = 0;
  auto alloc = [&](size_t bytes) {
    void* r = basep + off;
    off += (bytes + 255) & ~(size_t)255;
    return r;
  };
  // POSW first: per-pair 32 planes default; upgrade to 64 only if it fits.
  const size_t PLANE = (size_t)NM * 2;
  const size_t OTHER = (size_t)100 * 1024 * 1024;
  bool full4 = ws_size >= 64 * PLANE + OTHER;
  bf16* POSW = (bf16*)alloc((full4 ? 64 : 32) * PLANE);

  bf16* pooledB = (bf16*)alloc((size_t)4096 * 2048 * 2);      // later reused as Qb
  bf16* fc1T    = (bf16*)alloc((size_t)1024 * 2048 * 2);
  bf16* fc2T    = (bf16*)alloc((size_t)1024 * 1024 * 2);
  bf16* wqT     = (bf16*)alloc((size_t)4 * 1024 * 1024 * 2);  // [wq0T|wq1T|wq2T|wq3T]
  bf16* kvw     = (bf16*)alloc((size_t)8 * 1024 * 1024 * 2);  // [wk0T|wk1T|wc0|wc1 | wk2T|wk3T|wc2|wc3]
  float* P1     = (float*)alloc((size_t)4096 * 1024 * 4);     // f32 residual carry
  bf16* X1      = (bf16*)alloc((size_t)4096 * 1024 * 2);      // bf16 twin of P1
  bf16* KVb     = (bf16*)alloc((size_t)384 * 2048 * 2);       // K proj, pair layout
  bf16* Vb      = (bf16*)alloc((size_t)384 * 2048 * 2);       // V proj, ROW-major
  bf16* X2      = (bf16*)alloc((size_t)4096 * 1024 * 2);      // mid activations
  bf16* Qb      = pooledB;                                    // alias: dead after fc1

  if (full4) pos_kernel<4><<<dim3(NM / 128), dim3(256), 0, stream>>>(pe, awp, abp, POSW, 0);
  else       pos_kernel<2><<<dim3(NM / 128), dim3(256), 0, stream>>>(pe, awp, abp, POSW, 0);

  // casts / transposes of weights & input
  cast_kernel<<<dim3(4096, 1), dim3(256), 0, stream>>>(pooled, pooledB, 4096 * 2048 / 8, 0, 0, 0);
  tcast_kernel<<<dim3(512, 1), dim3(256), 0, stream>>>(fc1w, fc1T, 2048, 1024, 0, 0, 0);
  tcast_kernel<<<dim3(256, 1), dim3(256), 0, stream>>>(fc2w, fc2T, 1024, 1024, 0, 0, 0);
  tcast_kernel<<<dim3(256, 4), dim3(256), 0, stream>>>(awq, wqT, 1024, 1024, 1048576, 1048576, 2097152);
  tcast_kernel<<<dim3(256, 4), dim3(256), 0, stream>>>(awk, kvw, 1024, 1024, 1048576, 1048576, 4194304);
  cast_kernel<<<dim3(512, 4), dim3(256), 0, stream>>>(awc, kvw + 2097152, 131072, 1048576, 1048576, 4194304);

  // P1/X1 = pooled @ fc1 + b
  gemm64_kernel<<<dim3(64 * 8), dim3(256), 0, stream>>>(
      pooledB, 2048, fc1T, 2048, fc1b, 1024, P1, X1, 1024, 1024, 2048);
  // pair-0 projections: Q, K, V (all row-major epilogue)
  gemm64_kernel<<<dim3(64 * 16), dim3(256), 0, stream>>>(
      X1, 1024, wqT, 1024, abq, 2048, (float*)nullptr, Qb, 2048, 2048, 1024);
  gemm64_kernel<<<dim3(6 * 16), dim3(256), 0, stream>>>(
      X1, 1024, kvw, 1024, abk, 2048, (float*)nullptr, KVb, 2048, 2048, 1024);
  gemm64_kernel<<<dim3(6 * 16), dim3(256), 0, stream>>>(
      X1, 1024, kvw + 2097152, 1024, (const float*)nullptr, 0, (float*)nullptr, Vb, 2048, 2048, 1024);
  // X2 = bf16(P1 + attn0 - attn1)
  attn_simple_kernel<<<dim3(4096, 16), dim3(256), 0, stream>>>(
      Qb, KVb, Vb, POSW, P1, abc, abc + 1024, (float*)nullptr, X2);
  if (!full4) pos_kernel<2><<<dim3(NM / 128), dim3(256), 0, stream>>>(pe, awp, abp, POSW, 2);
  // P1/X1 = X2 @ fc2 + b
  gemm64_kernel<<<dim3(64 * 8), dim3(256), 0, stream>>>(
      X2, 1024, fc2T, 1024, fc2b, 1024, P1, X1, 1024, 1024, 1024);
  // pair-1 projections
  gemm64_kernel<<<dim3(64 * 16), dim3(256), 0, stream>>>(
      X1, 1024, wqT + (size_t)2 * 1048576, 1024, abq + 2048, 2048, (float*)nullptr, Qb, 2048, 2048, 1024);
  gemm64_kernel<<<dim3(6 * 16), dim3(256), 0, stream>>>(
      X1, 1024, kvw + (size_t)4 * 1048576, 1024, abk + 2048, 2048, (float*)nullptr, KVb, 2048, 2048, 1024);
  gemm64_kernel<<<dim3(6 * 16), dim3(256), 0, stream>>>(
      X1, 1024, kvw + (size_t)6 * 1048576, 1024, (const float*)nullptr, 0, (float*)nullptr, Vb, 2048, 2048, 1024);
  // out = P1 + attn2 - attn3  (f32)
  attn_simple_kernel<<<dim3(4096, 16), dim3(256), 0, stream>>>(
      Qb, KVb, Vb, POSW + (full4 ? (size_t)32 * NM : 0), P1, abc + 2048, abc + 3072, out, (bf16*)nullptr);
}